// Round 7
// baseline (566.314 us; speedup 1.0000x reference)
//
#include <hip/hip_runtime.h>
#include <math.h>

typedef unsigned short u16;
typedef __attribute__((ext_vector_type(8))) __bf16 bfx8;
typedef __attribute__((ext_vector_type(4))) float f32x4;
typedef __attribute__((ext_vector_type(8))) unsigned short us8;
typedef __attribute__((ext_vector_type(4))) unsigned short us4;

__device__ inline float bf2f(u16 u) {
    union { unsigned int i; float f; } v;
    v.i = ((unsigned int)u) << 16;
    return v.f;
}
__device__ inline u16 f2bf(float f) {
    union { float f; unsigned int i; } v;
    v.f = f;
    unsigned int b = v.i;
    return (u16)((b + 0x7FFFu + ((b >> 16) & 1u)) >> 16);
}

// ---------------- CSR build ----------------

__global__ void k_zero_int(int* __restrict__ p, int n) {
    int i = blockIdx.x * blockDim.x + threadIdx.x;
    if (i < n) p[i] = 0;
}

// single atomic pass: count + record local offset (coalesced store by edge id)
__global__ __launch_bounds__(256) void k_count_loc(const int* __restrict__ ei,
                                                   int* __restrict__ cnt,
                                                   int* __restrict__ lo, int E) {
    int base = (blockIdx.x * blockDim.x + threadIdx.x) * 4;
    if (base + 4 <= E) {
        int4 d = *(const int4*)(ei + E + base);
        int l0 = atomicAdd(&cnt[d.x], 1);
        int l1 = atomicAdd(&cnt[d.y], 1);
        int l2 = atomicAdd(&cnt[d.z], 1);
        int l3 = atomicAdd(&cnt[d.w], 1);
        *(int4*)(lo + base) = make_int4(l0, l1, l2, l3);
    } else {
        for (int e = base; e < E; ++e) {
            lo[e] = atomicAdd(&cnt[ei[E + e]], 1);
        }
    }
}

__global__ __launch_bounds__(256) void k_partial(const int* __restrict__ cnt,
                                                 int* __restrict__ partials, int n) {
    __shared__ int sdata[256];
    int base = blockIdx.x * 512;
    int t = threadIdx.x;
    int v = 0;
    if (base + t < n) v += cnt[base + t];
    if (base + 256 + t < n) v += cnt[base + 256 + t];
    sdata[t] = v;
    __syncthreads();
    for (int s = 128; s > 0; s >>= 1) {
        if (t < s) sdata[t] += sdata[t + s];
        __syncthreads();
    }
    if (t == 0) partials[blockIdx.x] = sdata[0];
}

__global__ __launch_bounds__(256) void k_scan_top(const int* __restrict__ partials,
                                                  int* __restrict__ blkoff, int nb) {
    __shared__ int lds[256];
    int t = threadIdx.x;
    int v = (t < nb) ? partials[t] : 0;
    lds[t] = v;
    __syncthreads();
    for (int off = 1; off < 256; off <<= 1) {
        int x = lds[t];
        int y = (t >= off) ? lds[t - off] : 0;
        __syncthreads();
        lds[t] = x + y;
        __syncthreads();
    }
    if (t < nb) blkoff[t] = lds[t] - v;   // exclusive
}

__global__ __launch_bounds__(512) void k_apply(const int* __restrict__ cnt,
                                               const int* __restrict__ blkoff,
                                               int* __restrict__ row_ptr,
                                               float* __restrict__ dinv,
                                               int n, int Etot) {
    __shared__ int lds[512];
    int b = blockIdx.x, t = threadIdx.x;
    int i = b * 512 + t;
    int v = (i < n) ? cnt[i] : 0;
    lds[t] = v;
    __syncthreads();
    for (int off = 1; off < 512; off <<= 1) {
        int x = lds[t];
        int y = (t >= off) ? lds[t - off] : 0;
        __syncthreads();
        lds[t] = x + y;
        __syncthreads();
    }
    if (i < n) {
        int excl = blkoff[b] + lds[t] - v;
        row_ptr[i] = excl;
        dinv[i] = rsqrtf((float)v + 1.0f);
    }
    if (i == 0) row_ptr[n] = Etot;
}

// atomic-free placement: csr_src[row_ptr[d] + lo[e]] = s
__global__ __launch_bounds__(256) void k_place(const int* __restrict__ ei,
                                               const int* __restrict__ row_ptr,
                                               const int* __restrict__ lo,
                                               int* __restrict__ csr_src, int E) {
    int base = (blockIdx.x * blockDim.x + threadIdx.x) * 4;
    if (base + 4 <= E) {
        int4 s = *(const int4*)(ei + base);
        int4 d = *(const int4*)(ei + E + base);
        int4 l = *(const int4*)(lo + base);
        int p0 = row_ptr[d.x] + l.x;
        int p1 = row_ptr[d.y] + l.y;
        int p2 = row_ptr[d.z] + l.z;
        int p3 = row_ptr[d.w] + l.w;
        csr_src[p0] = s.x;
        csr_src[p1] = s.y;
        csr_src[p2] = s.z;
        csr_src[p3] = s.w;
    } else {
        for (int e = base; e < E; ++e) {
            csr_src[row_ptr[ei[E + e]] + lo[e]] = ei[e];
        }
    }
}

// ---------------- small converts ----------------

__global__ void k_bnfold(const float* __restrict__ b, const float* __restrict__ g,
                         const float* __restrict__ be, const float* __restrict__ m,
                         const float* __restrict__ v, float* __restrict__ s,
                         float* __restrict__ t, int H) {
    int i = blockIdx.x * blockDim.x + threadIdx.x;
    if (i < H) {
        float sc = g[i] * rsqrtf(v[i] + 1e-5f);
        s[i] = sc;
        t[i] = (b[i] - m[i]) * sc + be[i];
    }
}

// W[K,F] f32 -> Wt[F,K] bf16
__global__ void k_w2bf(const float* __restrict__ W, u16* __restrict__ Wt, int K, int F) {
    int i = blockIdx.x * blockDim.x + threadIdx.x;
    if (i < K * F) {
        int k = i / F, f = i % F;
        Wt[(size_t)f * K + k] = f2bf(W[i]);
    }
}

// x f32 -> bf16 pre-scaled by dinv[row]  (row = i4/32 for F=128)
__global__ void k_x2bf(const float* __restrict__ x, u16* __restrict__ xb,
                       const float* __restrict__ dinv, int n4) {
    int i = blockIdx.x * blockDim.x + threadIdx.x;
    if (i < n4) {
        float d = dinv[i >> 5];
        float4 v = *(const float4*)(x + (size_t)i * 4);
        us4 o;
        o.x = f2bf(v.x * d); o.y = f2bf(v.y * d); o.z = f2bf(v.z * d); o.w = f2bf(v.w * d);
        *(us4*)(xb + (size_t)i * 4) = o;
    }
}

// ---------------- MFMA GEMM (register-pipelined, no LDS) ----------------
// C[M,Ftot] = A_bf16[M,K] @ Wt_bf16[Ftot,K]^T.
// Double-buffered register prefetch: loads for step kk+1 issue before step
// kk's MFMAs, so ~NF+1 loads are in flight per wave at all times.
// MODE 1: BN+ReLU then * dinv[row], bf16 store.  MODE 2: plain bf16 store.
template<int K, int FT, int MODE>
__global__ __launch_bounds__(256) void g_mfma(const u16* __restrict__ A,
                                              const u16* __restrict__ Wt,
                                              void* __restrict__ Cv, int M, int Ftot,
                                              const float* __restrict__ s,
                                              const float* __restrict__ t,
                                              const float* __restrict__ dinv) {
    int tid = threadIdx.x;
    int w = tid >> 6, l = tid & 63;
    int row0 = blockIdx.x * 64;
    int col0 = blockIdx.y * FT;
    int lr = l & 15;
    int koff = (l >> 4) * 8;

    int arow = row0 + w * 16 + lr;
    int arow_ld = (arow < M) ? arow : 0;
    const u16* ap = A + (size_t)arow_ld * K + koff;
    const u16* wp = Wt + (size_t)(col0 + lr) * K + koff;

    constexpr int NF = FT / 16;
    constexpr int NK = K / 32;
    f32x4 acc[NF];
    #pragma unroll
    for (int c = 0; c < NF; ++c) acc[c] = (f32x4){0.f, 0.f, 0.f, 0.f};

    bfx8 aC, aN;
    bfx8 bC[NF], bN[NF];

    aC = *(const bfx8*)(ap);
    #pragma unroll
    for (int c = 0; c < NF; ++c) bC[c] = *(const bfx8*)(wp + (size_t)c * 16 * K);

    #pragma unroll
    for (int kk = 0; kk < NK; ++kk) {
        if (kk + 1 < NK) {
            aN = *(const bfx8*)(ap + (kk + 1) * 32);
            #pragma unroll
            for (int c = 0; c < NF; ++c)
                bN[c] = *(const bfx8*)(wp + (size_t)c * 16 * K + (kk + 1) * 32);
        }
        #pragma unroll
        for (int c = 0; c < NF; ++c)
            acc[c] = __builtin_amdgcn_mfma_f32_16x16x32_bf16(aC, bC[c], acc[c], 0, 0, 0);
        if (kk + 1 < NK) {
            aC = aN;
            #pragma unroll
            for (int c = 0; c < NF; ++c) bC[c] = bN[c];
        }
    }

    int orow = row0 + w * 16 + (l >> 4) * 4;
    u16* C = (u16*)Cv;
    if (MODE == 1) {
        float dr[4];
        #pragma unroll
        for (int r = 0; r < 4; ++r) dr[r] = (orow + r < M) ? dinv[orow + r] : 0.f;
        #pragma unroll
        for (int c = 0; c < NF; ++c) {
            int gc = col0 + c * 16 + lr;
            float sc = s[gc], tc = t[gc];
            #pragma unroll
            for (int r = 0; r < 4; ++r) {
                int gr = orow + r;
                if (gr < M)
                    C[(size_t)gr * Ftot + gc] = f2bf(fmaxf(acc[c][r] * sc + tc, 0.f) * dr[r]);
            }
        }
    } else {
        #pragma unroll
        for (int c = 0; c < NF; ++c) {
            int gc = col0 + c * 16 + lr;
            #pragma unroll
            for (int r = 0; r < 4; ++r) {
                int gr = orow + r;
                if (gr < M) C[(size_t)gr * Ftot + gc] = f2bf(acc[c][r]);
            }
        }
    }
}

// ---------------- Aggregation ----------------
// Inputs are pre-scaled by dinv[src]; output = dinv[node] * (self + sum).
// agg_x: F=128 bf16. 32 lanes/node, lane owns 4 features (8B). 2 nodes/wave.
__global__ __launch_bounds__(256) void agg_x(const u16* __restrict__ in,
                                             u16* __restrict__ outp,
                                             const int* __restrict__ row_ptr,
                                             const int* __restrict__ csr_src,
                                             const float* __restrict__ dinv,
                                             int nnodes) {
    int tid = threadIdx.x;
    int wv = tid >> 6, lane = tid & 63;
    int half = lane >> 5, l32 = lane & 31;
    int node = (blockIdx.x * 4 + wv) * 2 + half;
    if (node >= nnodes) return;
    int off = l32 * 4;
    const u16* bp = in + off;
    us4 su = *(const us4*)(in + (size_t)node * 128 + off);
    float a0 = bf2f(su.x), a1 = bf2f(su.y), a2 = bf2f(su.z), a3 = bf2f(su.w);
    int e = row_ptr[node], e1 = row_ptr[node + 1];
    for (; e + 4 <= e1; e += 4) {
        int s0 = csr_src[e], s1 = csr_src[e + 1], s2 = csr_src[e + 2], s3 = csr_src[e + 3];
        us4 v0 = *(const us4*)(bp + (size_t)s0 * 128);
        us4 v1 = *(const us4*)(bp + (size_t)s1 * 128);
        us4 v2 = *(const us4*)(bp + (size_t)s2 * 128);
        us4 v3 = *(const us4*)(bp + (size_t)s3 * 128);
        a0 += bf2f(v0.x) + bf2f(v1.x) + bf2f(v2.x) + bf2f(v3.x);
        a1 += bf2f(v0.y) + bf2f(v1.y) + bf2f(v2.y) + bf2f(v3.y);
        a2 += bf2f(v0.z) + bf2f(v1.z) + bf2f(v2.z) + bf2f(v3.z);
        a3 += bf2f(v0.w) + bf2f(v1.w) + bf2f(v2.w) + bf2f(v3.w);
    }
    for (; e < e1; ++e) {
        int s0 = csr_src[e];
        us4 v0 = *(const us4*)(bp + (size_t)s0 * 128);
        a0 += bf2f(v0.x); a1 += bf2f(v0.y);
        a2 += bf2f(v0.z); a3 += bf2f(v0.w);
    }
    float d = dinv[node];
    us4 o;
    o.x = f2bf(a0 * d); o.y = f2bf(a1 * d); o.z = f2bf(a2 * d); o.w = f2bf(a3 * d);
    *(us4*)(outp + (size_t)node * 128 + off) = o;
}

// agg_h: F=256 bf16. 32 lanes/node, lane owns 8 features (16B). 2 nodes/wave.
__global__ __launch_bounds__(256) void agg_h(const u16* __restrict__ in,
                                             u16* __restrict__ outp,
                                             const int* __restrict__ row_ptr,
                                             const int* __restrict__ csr_src,
                                             const float* __restrict__ dinv,
                                             int nnodes) {
    int tid = threadIdx.x;
    int wv = tid >> 6, lane = tid & 63;
    int half = lane >> 5, l32 = lane & 31;
    int node = (blockIdx.x * 4 + wv) * 2 + half;
    if (node >= nnodes) return;
    int off = l32 * 8;
    const u16* bp = in + off;
    float acc[8];
    us8 su = *(const us8*)(in + (size_t)node * 256 + off);
    #pragma unroll
    for (int j = 0; j < 8; ++j) acc[j] = bf2f(su[j]);
    int e = row_ptr[node], e1 = row_ptr[node + 1];
    for (; e + 4 <= e1; e += 4) {
        int s0 = csr_src[e], s1 = csr_src[e + 1], s2 = csr_src[e + 2], s3 = csr_src[e + 3];
        us8 v0 = *(const us8*)(bp + (size_t)s0 * 256);
        us8 v1 = *(const us8*)(bp + (size_t)s1 * 256);
        us8 v2 = *(const us8*)(bp + (size_t)s2 * 256);
        us8 v3 = *(const us8*)(bp + (size_t)s3 * 256);
        #pragma unroll
        for (int j = 0; j < 8; ++j)
            acc[j] += bf2f(v0[j]) + bf2f(v1[j]) + bf2f(v2[j]) + bf2f(v3[j]);
    }
    for (; e < e1; ++e) {
        int s0 = csr_src[e];
        us8 v0 = *(const us8*)(bp + (size_t)s0 * 256);
        #pragma unroll
        for (int j = 0; j < 8; ++j) acc[j] += bf2f(v0[j]);
    }
    float d = dinv[node];
    us8 o;
    #pragma unroll
    for (int j = 0; j < 8; ++j) o[j] = f2bf(acc[j] * d);
    *(us8*)(outp + (size_t)node * 256 + off) = o;
}

// agg32: F=32 bf16 in (pre-scaled), f32 sigmoid out. 32 lanes/node, 2 nodes/wave.
__global__ __launch_bounds__(256) void agg32_sig(const u16* __restrict__ z,
                                                 float* __restrict__ out,
                                                 const int* __restrict__ row_ptr,
                                                 const int* __restrict__ csr_src,
                                                 const float* __restrict__ dinv,
                                                 const float* __restrict__ b3,
                                                 int nnodes) {
    int tid = threadIdx.x;
    int wv = tid >> 6, lane = tid & 63;
    int half = lane >> 5, l32 = lane & 31;
    int node = (blockIdx.x * 4 + wv) * 2 + half;
    if (node >= nnodes) return;
    float acc = bf2f(z[(size_t)node * 32 + l32]);
    int e = row_ptr[node], e1 = row_ptr[node + 1];
    for (; e + 4 <= e1; e += 4) {
        int s0 = csr_src[e], s1 = csr_src[e + 1], s2 = csr_src[e + 2], s3 = csr_src[e + 3];
        float z0 = bf2f(z[(size_t)s0 * 32 + l32]);
        float z1 = bf2f(z[(size_t)s1 * 32 + l32]);
        float z2 = bf2f(z[(size_t)s2 * 32 + l32]);
        float z3v = bf2f(z[(size_t)s3 * 32 + l32]);
        acc += z0 + z1 + z2 + z3v;
    }
    for (; e < e1; ++e) {
        acc += bf2f(z[(size_t)csr_src[e] * 32 + l32]);
    }
    acc = acc * dinv[node] + b3[l32];
    out[(size_t)node * 32 + l32] = 1.f / (1.f + expf(-acc));
}

// ---------------- launch ----------------

extern "C" void kernel_launch(void* const* d_in, const int* in_sizes, int n_in,
                              void* d_out, int out_size, void* d_ws, size_t ws_size,
                              hipStream_t stream) {
    const float* x  = (const float*)d_in[0];
    const int*   ei = (const int*)d_in[1];
    const float* W1 = (const float*)d_in[2];
    const float* b1 = (const float*)d_in[3];
    const float* g1 = (const float*)d_in[4];
    const float* be1 = (const float*)d_in[5];
    const float* m1 = (const float*)d_in[6];
    const float* v1 = (const float*)d_in[7];
    const float* W2 = (const float*)d_in[8];
    const float* b2 = (const float*)d_in[9];
    const float* g2 = (const float*)d_in[10];
    const float* be2 = (const float*)d_in[11];
    const float* m2 = (const float*)d_in[12];
    const float* v2 = (const float*)d_in[13];
    const float* W3 = (const float*)d_in[14];
    const float* b3 = (const float*)d_in[15];
    float* out = (float*)d_out;

    const int N = in_sizes[0] / 128;   // 100000
    const int E = in_sizes[1] / 2;     // 1600000

    char* w = (char*)d_ws;
    auto alloc = [&](size_t bytes) -> void* {
        void* p = (void*)w;
        w += (bytes + 255) & ~(size_t)255;
        return p;
    };
    int* cnt      = (int*)alloc((size_t)N * 4);
    int* row_ptr  = (int*)alloc((size_t)(N + 1) * 4);
    int* lo       = (int*)alloc((size_t)E * 4);
    float* dinv   = (float*)alloc((size_t)N * 4);
    int* partials = (int*)alloc(256 * 4);
    int* blkoff   = (int*)alloc(256 * 4);
    float* s1 = (float*)alloc(256 * 4);
    float* t1 = (float*)alloc(256 * 4);
    float* s2 = (float*)alloc(256 * 4);
    float* t2 = (float*)alloc(256 * 4);
    u16* Wt1 = (u16*)alloc((size_t)128 * 256 * 2);
    u16* Wt2 = (u16*)alloc((size_t)256 * 256 * 2);
    u16* Wt3 = (u16*)alloc((size_t)256 * 32 * 2);
    int* csr_src = (int*)alloc((size_t)E * 4);
    u16* xbf  = (u16*)alloc((size_t)N * 128 * 2);   // x*dinv bf16; later reused as z3
    u16* bufA = (u16*)alloc((size_t)N * 256 * 2);
    u16* bufB = (u16*)alloc((size_t)N * 256 * 2);
    u16* z3 = xbf;   // N*32 bf16, xbf dead after layer 1

    int nb = (N + 511) / 512;
    int gx = (N + 63) / 64;
    int gagg = (N + 7) / 8;          // 8 nodes per block (4 waves x 2)
    int ge4 = (E / 4 + 255) / 256;   // 4 edges per thread

    // CSR build: one atomic pass + scan + atomic-free placement
    k_zero_int<<<(N + 255) / 256, 256, 0, stream>>>(cnt, N);
    k_count_loc<<<ge4, 256, 0, stream>>>(ei, cnt, lo, E);
    k_partial<<<nb, 256, 0, stream>>>(cnt, partials, N);
    k_scan_top<<<1, 256, 0, stream>>>(partials, blkoff, nb);
    k_apply<<<nb, 512, 0, stream>>>(cnt, blkoff, row_ptr, dinv, N, E);
    k_place<<<ge4, 256, 0, stream>>>(ei, row_ptr, lo, csr_src, E);

    // param prep
    k_bnfold<<<1, 256, 0, stream>>>(b1, g1, be1, m1, v1, s1, t1, 256);
    k_bnfold<<<1, 256, 0, stream>>>(b2, g2, be2, m2, v2, s2, t2, 256);
    k_w2bf<<<(128 * 256 + 255) / 256, 256, 0, stream>>>(W1, Wt1, 128, 256);
    k_w2bf<<<(256 * 256 + 255) / 256, 256, 0, stream>>>(W2, Wt2, 256, 256);
    k_w2bf<<<(256 * 32 + 255) / 256, 256, 0, stream>>>(W3, Wt3, 256, 32);
    k_x2bf<<<(N * 128 / 4 + 255) / 256, 256, 0, stream>>>(x, xbf, dinv, N * 128 / 4);

    // Layer 1: agg(xs,128) -> GEMM(128->256)+BN+ReLU+dinv -> bf16 (pre-scaled)
    agg_x<<<gagg, 256, 0, stream>>>(xbf, bufA, row_ptr, csr_src, dinv, N);
    g_mfma<128, 128, 1><<<dim3(gx, 2), 256, 0, stream>>>(bufA, Wt1, bufB, N, 256, s1, t1, dinv);

    // Layer 2: agg(h1s,256) -> GEMM(256->256)+BN+ReLU+dinv -> bf16 (pre-scaled)
    agg_h<<<gagg, 256, 0, stream>>>(bufB, bufA, row_ptr, csr_src, dinv, N);
    g_mfma<256, 128, 1><<<dim3(gx, 2), 256, 0, stream>>>(bufA, Wt2, bufB, N, 256, s2, t2, dinv);

    // Layer 3: GEMM(256->32) -> bf16 (rows carry dinv), then agg + b3 + sigmoid
    g_mfma<256, 32, 2><<<dim3(gx, 1), 256, 0, stream>>>(bufB, Wt3, (void*)z3, N, 32,
                                                        (const float*)nullptr,
                                                        (const float*)nullptr,
                                                        (const float*)nullptr);
    agg32_sig<<<gagg, 256, 0, stream>>>(z3, out, row_ptr, csr_src, dinv, b3, N);
}

// Round 8
// 420.865 us; speedup vs baseline: 1.3456x; 1.3456x over previous
//
#include <hip/hip_runtime.h>
#include <math.h>

typedef unsigned short u16;
typedef __attribute__((ext_vector_type(8))) __bf16 bfx8;
typedef __attribute__((ext_vector_type(4))) float f32x4;
typedef __attribute__((ext_vector_type(8))) unsigned short us8;
typedef __attribute__((ext_vector_type(4))) unsigned short us4;

__device__ inline float bf2f(u16 u) {
    union { unsigned int i; float f; } v;
    v.i = ((unsigned int)u) << 16;
    return v.f;
}
__device__ inline u16 f2bf(float f) {
    union { float f; unsigned int i; } v;
    v.f = f;
    unsigned int b = v.i;
    return (u16)((b + 0x7FFFu + ((b >> 16) & 1u)) >> 16);
}

// ---------------- CSR build ----------------

__global__ void k_zero_int(int* __restrict__ p, int n) {
    int i = blockIdx.x * blockDim.x + threadIdx.x;
    if (i < n) p[i] = 0;
}

// single atomic pass: count + record local offset (coalesced store by edge id)
__global__ __launch_bounds__(256) void k_count_loc(const int* __restrict__ ei,
                                                   int* __restrict__ cnt,
                                                   int* __restrict__ lo, int E) {
    int base = (blockIdx.x * blockDim.x + threadIdx.x) * 4;
    if (base + 4 <= E) {
        int4 d = *(const int4*)(ei + E + base);
        int l0 = atomicAdd(&cnt[d.x], 1);
        int l1 = atomicAdd(&cnt[d.y], 1);
        int l2 = atomicAdd(&cnt[d.z], 1);
        int l3 = atomicAdd(&cnt[d.w], 1);
        *(int4*)(lo + base) = make_int4(l0, l1, l2, l3);
    } else {
        for (int e = base; e < E; ++e) {
            lo[e] = atomicAdd(&cnt[ei[E + e]], 1);
        }
    }
}

__global__ __launch_bounds__(256) void k_partial(const int* __restrict__ cnt,
                                                 int* __restrict__ partials, int n) {
    __shared__ int sdata[256];
    int base = blockIdx.x * 512;
    int t = threadIdx.x;
    int v = 0;
    if (base + t < n) v += cnt[base + t];
    if (base + 256 + t < n) v += cnt[base + 256 + t];
    sdata[t] = v;
    __syncthreads();
    for (int s = 128; s > 0; s >>= 1) {
        if (t < s) sdata[t] += sdata[t + s];
        __syncthreads();
    }
    if (t == 0) partials[blockIdx.x] = sdata[0];
}

__global__ __launch_bounds__(256) void k_scan_top(const int* __restrict__ partials,
                                                  int* __restrict__ blkoff, int nb) {
    __shared__ int lds[256];
    int t = threadIdx.x;
    int v = (t < nb) ? partials[t] : 0;
    lds[t] = v;
    __syncthreads();
    for (int off = 1; off < 256; off <<= 1) {
        int x = lds[t];
        int y = (t >= off) ? lds[t - off] : 0;
        __syncthreads();
        lds[t] = x + y;
        __syncthreads();
    }
    if (t < nb) blkoff[t] = lds[t] - v;   // exclusive
}

__global__ __launch_bounds__(512) void k_apply(const int* __restrict__ cnt,
                                               const int* __restrict__ blkoff,
                                               int* __restrict__ row_ptr,
                                               float* __restrict__ dinv,
                                               int n, int Etot) {
    __shared__ int lds[512];
    int b = blockIdx.x, t = threadIdx.x;
    int i = b * 512 + t;
    int v = (i < n) ? cnt[i] : 0;
    lds[t] = v;
    __syncthreads();
    for (int off = 1; off < 512; off <<= 1) {
        int x = lds[t];
        int y = (t >= off) ? lds[t - off] : 0;
        __syncthreads();
        lds[t] = x + y;
        __syncthreads();
    }
    if (i < n) {
        int excl = blkoff[b] + lds[t] - v;
        row_ptr[i] = excl;
        dinv[i] = rsqrtf((float)v + 1.0f);
    }
    if (i == 0) row_ptr[n] = Etot;
}

// atomic-free placement: csr_src[row_ptr[d] + lo[e]] = s
__global__ __launch_bounds__(256) void k_place(const int* __restrict__ ei,
                                               const int* __restrict__ row_ptr,
                                               const int* __restrict__ lo,
                                               int* __restrict__ csr_src, int E) {
    int base = (blockIdx.x * blockDim.x + threadIdx.x) * 4;
    if (base + 4 <= E) {
        int4 s = *(const int4*)(ei + base);
        int4 d = *(const int4*)(ei + E + base);
        int4 l = *(const int4*)(lo + base);
        int p0 = row_ptr[d.x] + l.x;
        int p1 = row_ptr[d.y] + l.y;
        int p2 = row_ptr[d.z] + l.z;
        int p3 = row_ptr[d.w] + l.w;
        csr_src[p0] = s.x;
        csr_src[p1] = s.y;
        csr_src[p2] = s.z;
        csr_src[p3] = s.w;
    } else {
        for (int e = base; e < E; ++e) {
            csr_src[row_ptr[ei[E + e]] + lo[e]] = ei[e];
        }
    }
}

// ---------------- small converts ----------------

__global__ void k_bnfold(const float* __restrict__ b, const float* __restrict__ g,
                         const float* __restrict__ be, const float* __restrict__ m,
                         const float* __restrict__ v, float* __restrict__ s,
                         float* __restrict__ t, int H) {
    int i = blockIdx.x * blockDim.x + threadIdx.x;
    if (i < H) {
        float sc = g[i] * rsqrtf(v[i] + 1e-5f);
        s[i] = sc;
        t[i] = (b[i] - m[i]) * sc + be[i];
    }
}

// W[K,F] f32 -> Wt[F,K] bf16
__global__ void k_w2bf(const float* __restrict__ W, u16* __restrict__ Wt, int K, int F) {
    int i = blockIdx.x * blockDim.x + threadIdx.x;
    if (i < K * F) {
        int k = i / F, f = i % F;
        Wt[(size_t)f * K + k] = f2bf(W[i]);
    }
}

// x f32 -> bf16 pre-scaled by dinv[row]  (row = i4/32 for F=128)
__global__ void k_x2bf(const float* __restrict__ x, u16* __restrict__ xb,
                       const float* __restrict__ dinv, int n4) {
    int i = blockIdx.x * blockDim.x + threadIdx.x;
    if (i < n4) {
        float d = dinv[i >> 5];
        float4 v = *(const float4*)(x + (size_t)i * 4);
        us4 o;
        o.x = f2bf(v.x * d); o.y = f2bf(v.y * d); o.z = f2bf(v.z * d); o.w = f2bf(v.w * d);
        *(us4*)(xb + (size_t)i * 4) = o;
    }
}

// ---------------- MFMA GEMM: persistent blocks, B in registers, A via LDS ---
// C[M,Ftot] = A_bf16[M,K] @ Wt_bf16[Ftot,K]^T
// Block: 256 threads (4 waves), tile = 64 rows x FT cols, persistent over
// row-tiles (stride gridDim.x). B fragments for this block's FT cols are
// loaded ONCE into registers. A is staged through double-buffered LDS
// mini-tiles (64 x BK=128 elems) via coalesced reg loads issued 2 minis
// ahead (T14 async split). C goes out through LDS for coalesced stores.
// MODE 1: BN+ReLU then * dinv[row], bf16. MODE 2: plain bf16.
template<int K, int FT, int MODE, int MINW>
__global__ __launch_bounds__(256, MINW) void g_mfma_lds(
    const u16* __restrict__ A, const u16* __restrict__ Wt,
    u16* __restrict__ C, int M, int Ftot,
    const float* __restrict__ s, const float* __restrict__ t,
    const float* __restrict__ dinv, int nTiles)
{
    constexpr int BK  = 128;          // elems per mini-tile (K-chunk)
    constexpr int SA  = BK + 8;       // padded LDS stride (elems) = 272B rows
    constexpr int NH  = K / BK;       // minis per tile (1 or 2)
    constexpr int NKH = BK / 32;      // MFMA K-steps per mini = 4
    constexpr int NF  = FT / 16;      // col fragments
    constexpr int SC  = FT + 8;       // padded C stride

    __shared__ u16 Asmem[2][64 * SA];
    __shared__ u16 Csmem[64 * SC];

    int tid = threadIdx.x;
    int w = tid >> 6, l = tid & 63;
    int lr = l & 15, koff8 = (l >> 4) * 8;
    int col0 = blockIdx.y * FT;

    // ---- B fragments in registers (once per block) ----
    bfx8 bfr[NH][NKH][NF];
    {
        const u16* wp = Wt + (size_t)(col0 + lr) * K + koff8;
        #pragma unroll
        for (int h = 0; h < NH; ++h)
            #pragma unroll
            for (int kk = 0; kk < NKH; ++kk)
                #pragma unroll
                for (int c = 0; c < NF; ++c)
                    bfr[h][kk][c] = *(const bfx8*)(wp + (size_t)c * 16 * K + h * BK + kk * 32);
    }

    int myT = (blockIdx.x < nTiles) ? ((nTiles - 1 - (int)blockIdx.x) / (int)gridDim.x + 1) : 0;
    int NM = myT * NH;
    if (NM == 0) return;

    f32x4 acc[NF];
    #pragma unroll
    for (int c = 0; c < NF; ++c) acc[c] = (f32x4){0.f, 0.f, 0.f, 0.f};

    us8 rga[4];

    // ---- prologue: stage mini 0, prefetch mini 1 ----
    {
        int row0 = blockIdx.x * 64;
        #pragma unroll
        for (int j = 0; j < 4; ++j) {
            int cid = j * 256 + tid;
            int row = cid >> 4, ch = cid & 15;
            int gr = row0 + row; if (gr > M - 1) gr = M - 1;
            rga[j] = *(const us8*)(A + (size_t)gr * K + 0 * BK + ch * 8);
        }
        #pragma unroll
        for (int j = 0; j < 4; ++j) {
            int cid = j * 256 + tid;
            int row = cid >> 4, ch = cid & 15;
            *(us8*)&Asmem[0][row * SA + ch * 8] = rga[j];
        }
        if (NM > 1) {
            constexpr int gt1 = 1 / NH, h1 = 1 % NH;
            int r0 = (blockIdx.x + gt1 * gridDim.x) * 64;
            #pragma unroll
            for (int j = 0; j < 4; ++j) {
                int cid = j * 256 + tid;
                int row = cid >> 4, ch = cid & 15;
                int gr = r0 + row; if (gr > M - 1) gr = M - 1;
                rga[j] = *(const us8*)(A + (size_t)gr * K + h1 * BK + ch * 8);
            }
        }
    }
    __syncthreads();

    int cur = 0, gm = 0;
    for (int ti = 0; ti < myT; ++ti) {
        int row0g = (blockIdx.x + ti * gridDim.x) * 64;
        #pragma unroll
        for (int h = 0; h < NH; ++h) {
            // ---- compute mini from Asmem[cur] ----
            const u16* ab = &Asmem[cur][0];
            #pragma unroll
            for (int kk = 0; kk < NKH; ++kk) {
                bfx8 af = *(const bfx8*)(ab + (w * 16 + lr) * SA + koff8 + kk * 32);
                #pragma unroll
                for (int c = 0; c < NF; ++c)
                    acc[c] = __builtin_amdgcn_mfma_f32_16x16x32_bf16(af, bfr[h][kk][c], acc[c], 0, 0, 0);
            }
            if (h == NH - 1) {
                // epilogue A: acc -> Csmem (bf16)
                int orow = w * 16 + (l >> 4) * 4;
                float dr[4];
                #pragma unroll
                for (int r = 0; r < 4; ++r) {
                    int grow = row0g + orow + r;
                    dr[r] = (MODE == 1) ? ((grow < M) ? dinv[grow] : 0.f) : 1.f;
                }
                #pragma unroll
                for (int c = 0; c < NF; ++c) {
                    int gc = col0 + c * 16 + lr;
                    float sc = (MODE == 1) ? s[gc] : 0.f;
                    float tc = (MODE == 1) ? t[gc] : 0.f;
                    #pragma unroll
                    for (int r = 0; r < 4; ++r) {
                        float v = acc[c][r];
                        u16 ov = (MODE == 1) ? f2bf(fmaxf(v * sc + tc, 0.f) * dr[r])
                                             : f2bf(v);
                        Csmem[(orow + r) * SC + c * 16 + lr] = ov;
                    }
                    acc[c] = (f32x4){0.f, 0.f, 0.f, 0.f};
                }
            }
            __syncthreads();
            // ---- phase 2: stage write, C store, prefetch ----
            if (gm + 1 < NM) {
                #pragma unroll
                for (int j = 0; j < 4; ++j) {
                    int cid = j * 256 + tid;
                    int row = cid >> 4, ch = cid & 15;
                    *(us8*)&Asmem[cur ^ 1][row * SA + ch * 8] = rga[j];
                }
            }
            if (h == NH - 1) {
                constexpr int CPR = FT / 8;            // 16B chunks per C row
                constexpr int CPT = (64 * CPR) / 256;  // chunks per thread
                #pragma unroll
                for (int j = 0; j < CPT; ++j) {
                    int cid = j * 256 + tid;
                    int crow = cid / CPR;
                    int ccol = (cid % CPR) * 8;
                    int grow = row0g + crow;
                    if (grow < M) {
                        us8 vv = *(const us8*)&Csmem[crow * SC + ccol];
                        *(us8*)(C + (size_t)grow * Ftot + col0 + ccol) = vv;
                    }
                }
            }
            if (gm + 2 < NM) {
                int g2 = gm + 2;
                int gt2 = g2 / NH, h2 = g2 % NH;
                int r0 = (blockIdx.x + gt2 * gridDim.x) * 64;
                #pragma unroll
                for (int j = 0; j < 4; ++j) {
                    int cid = j * 256 + tid;
                    int row = cid >> 4, ch = cid & 15;
                    int gr = r0 + row; if (gr > M - 1) gr = M - 1;
                    rga[j] = *(const us8*)(A + (size_t)gr * K + h2 * BK + ch * 8);
                }
            }
            __syncthreads();
            cur ^= 1; ++gm;
        }
    }
}

// ---------------- Aggregation ----------------
// Inputs are pre-scaled by dinv[src]; output = dinv[node] * (self + sum).
// agg_x: F=128 bf16. 32 lanes/node, lane owns 4 features (8B). 2 nodes/wave.
__global__ __launch_bounds__(256) void agg_x(const u16* __restrict__ in,
                                             u16* __restrict__ outp,
                                             const int* __restrict__ row_ptr,
                                             const int* __restrict__ csr_src,
                                             const float* __restrict__ dinv,
                                             int nnodes) {
    int tid = threadIdx.x;
    int wv = tid >> 6, lane = tid & 63;
    int half = lane >> 5, l32 = lane & 31;
    int node = (blockIdx.x * 4 + wv) * 2 + half;
    if (node >= nnodes) return;
    int off = l32 * 4;
    const u16* bp = in + off;
    us4 su = *(const us4*)(in + (size_t)node * 128 + off);
    float a0 = bf2f(su.x), a1 = bf2f(su.y), a2 = bf2f(su.z), a3 = bf2f(su.w);
    int e = row_ptr[node], e1 = row_ptr[node + 1];
    for (; e + 4 <= e1; e += 4) {
        int s0 = csr_src[e], s1 = csr_src[e + 1], s2 = csr_src[e + 2], s3 = csr_src[e + 3];
        us4 v0 = *(const us4*)(bp + (size_t)s0 * 128);
        us4 v1 = *(const us4*)(bp + (size_t)s1 * 128);
        us4 v2 = *(const us4*)(bp + (size_t)s2 * 128);
        us4 v3 = *(const us4*)(bp + (size_t)s3 * 128);
        a0 += bf2f(v0.x) + bf2f(v1.x) + bf2f(v2.x) + bf2f(v3.x);
        a1 += bf2f(v0.y) + bf2f(v1.y) + bf2f(v2.y) + bf2f(v3.y);
        a2 += bf2f(v0.z) + bf2f(v1.z) + bf2f(v2.z) + bf2f(v3.z);
        a3 += bf2f(v0.w) + bf2f(v1.w) + bf2f(v2.w) + bf2f(v3.w);
    }
    for (; e < e1; ++e) {
        int s0 = csr_src[e];
        us4 v0 = *(const us4*)(bp + (size_t)s0 * 128);
        a0 += bf2f(v0.x); a1 += bf2f(v0.y);
        a2 += bf2f(v0.z); a3 += bf2f(v0.w);
    }
    float d = dinv[node];
    us4 o;
    o.x = f2bf(a0 * d); o.y = f2bf(a1 * d); o.z = f2bf(a2 * d); o.w = f2bf(a3 * d);
    *(us4*)(outp + (size_t)node * 128 + off) = o;
}

// agg_h: F=256 bf16. 32 lanes/node, lane owns 8 features (16B). 2 nodes/wave.
__global__ __launch_bounds__(256) void agg_h(const u16* __restrict__ in,
                                             u16* __restrict__ outp,
                                             const int* __restrict__ row_ptr,
                                             const int* __restrict__ csr_src,
                                             const float* __restrict__ dinv,
                                             int nnodes) {
    int tid = threadIdx.x;
    int wv = tid >> 6, lane = tid & 63;
    int half = lane >> 5, l32 = lane & 31;
    int node = (blockIdx.x * 4 + wv) * 2 + half;
    if (node >= nnodes) return;
    int off = l32 * 8;
    const u16* bp = in + off;
    float acc[8];
    us8 su = *(const us8*)(in + (size_t)node * 256 + off);
    #pragma unroll
    for (int j = 0; j < 8; ++j) acc[j] = bf2f(su[j]);
    int e = row_ptr[node], e1 = row_ptr[node + 1];
    for (; e + 4 <= e1; e += 4) {
        int s0 = csr_src[e], s1 = csr_src[e + 1], s2 = csr_src[e + 2], s3 = csr_src[e + 3];
        us8 v0 = *(const us8*)(bp + (size_t)s0 * 256);
        us8 v1 = *(const us8*)(bp + (size_t)s1 * 256);
        us8 v2 = *(const us8*)(bp + (size_t)s2 * 256);
        us8 v3 = *(const us8*)(bp + (size_t)s3 * 256);
        #pragma unroll
        for (int j = 0; j < 8; ++j)
            acc[j] += bf2f(v0[j]) + bf2f(v1[j]) + bf2f(v2[j]) + bf2f(v3[j]);
    }
    for (; e < e1; ++e) {
        int s0 = csr_src[e];
        us8 v0 = *(const us8*)(bp + (size_t)s0 * 256);
        #pragma unroll
        for (int j = 0; j < 8; ++j) acc[j] += bf2f(v0[j]);
    }
    float d = dinv[node];
    us8 o;
    #pragma unroll
    for (int j = 0; j < 8; ++j) o[j] = f2bf(acc[j] * d);
    *(us8*)(outp + (size_t)node * 256 + off) = o;
}

// agg32: F=32 bf16 in (pre-scaled), f32 sigmoid out. 32 lanes/node, 2 nodes/wave.
__global__ __launch_bounds__(256) void agg32_sig(const u16* __restrict__ z,
                                                 float* __restrict__ out,
                                                 const int* __restrict__ row_ptr,
                                                 const int* __restrict__ csr_src,
                                                 const float* __restrict__ dinv,
                                                 const float* __restrict__ b3,
                                                 int nnodes) {
    int tid = threadIdx.x;
    int wv = tid >> 6, lane = tid & 63;
    int half = lane >> 5, l32 = lane & 31;
    int node = (blockIdx.x * 4 + wv) * 2 + half;
    if (node >= nnodes) return;
    float acc = bf2f(z[(size_t)node * 32 + l32]);
    int e = row_ptr[node], e1 = row_ptr[node + 1];
    for (; e + 4 <= e1; e += 4) {
        int s0 = csr_src[e], s1 = csr_src[e + 1], s2 = csr_src[e + 2], s3 = csr_src[e + 3];
        float z0 = bf2f(z[(size_t)s0 * 32 + l32]);
        float z1 = bf2f(z[(size_t)s1 * 32 + l32]);
        float z2 = bf2f(z[(size_t)s2 * 32 + l32]);
        float z3v = bf2f(z[(size_t)s3 * 32 + l32]);
        acc += z0 + z1 + z2 + z3v;
    }
    for (; e < e1; ++e) {
        acc += bf2f(z[(size_t)csr_src[e] * 32 + l32]);
    }
    acc = acc * dinv[node] + b3[l32];
    out[(size_t)node * 32 + l32] = 1.f / (1.f + expf(-acc));
}

// ---------------- launch ----------------

extern "C" void kernel_launch(void* const* d_in, const int* in_sizes, int n_in,
                              void* d_out, int out_size, void* d_ws, size_t ws_size,
                              hipStream_t stream) {
    const float* x  = (const float*)d_in[0];
    const int*   ei = (const int*)d_in[1];
    const float* W1 = (const float*)d_in[2];
    const float* b1 = (const float*)d_in[3];
    const float* g1 = (const float*)d_in[4];
    const float* be1 = (const float*)d_in[5];
    const float* m1 = (const float*)d_in[6];
    const float* v1 = (const float*)d_in[7];
    const float* W2 = (const float*)d_in[8];
    const float* b2 = (const float*)d_in[9];
    const float* g2 = (const float*)d_in[10];
    const float* be2 = (const float*)d_in[11];
    const float* m2 = (const float*)d_in[12];
    const float* v2 = (const float*)d_in[13];
    const float* W3 = (const float*)d_in[14];
    const float* b3 = (const float*)d_in[15];
    float* out = (float*)d_out;

    const int N = in_sizes[0] / 128;   // 100000
    const int E = in_sizes[1] / 2;     // 1600000

    char* w = (char*)d_ws;
    auto alloc = [&](size_t bytes) -> void* {
        void* p = (void*)w;
        w += (bytes + 255) & ~(size_t)255;
        return p;
    };
    int* cnt      = (int*)alloc((size_t)N * 4);
    int* row_ptr  = (int*)alloc((size_t)(N + 1) * 4);
    int* lo       = (int*)alloc((size_t)E * 4);
    float* dinv   = (float*)alloc((size_t)N * 4);
    int* partials = (int*)alloc(256 * 4);
    int* blkoff   = (int*)alloc(256 * 4);
    float* s1 = (float*)alloc(256 * 4);
    float* t1 = (float*)alloc(256 * 4);
    float* s2 = (float*)alloc(256 * 4);
    float* t2 = (float*)alloc(256 * 4);
    u16* Wt1 = (u16*)alloc((size_t)128 * 256 * 2);
    u16* Wt2 = (u16*)alloc((size_t)256 * 256 * 2);
    u16* Wt3 = (u16*)alloc((size_t)256 * 32 * 2);
    int* csr_src = (int*)alloc((size_t)E * 4);
    u16* xbf  = (u16*)alloc((size_t)N * 128 * 2);   // x*dinv bf16; later reused as z3
    u16* bufA = (u16*)alloc((size_t)N * 256 * 2);
    u16* bufB = (u16*)alloc((size_t)N * 256 * 2);
    u16* z3 = xbf;   // N*32 bf16, xbf dead after layer 1

    int nb = (N + 511) / 512;
    int nT = (N + 63) / 64;          // 64-row tiles
    int gagg = (N + 7) / 8;          // 8 nodes per block (4 waves x 2)
    int ge4 = (E / 4 + 255) / 256;   // 4 edges per thread

    // CSR build: one atomic pass + scan + atomic-free placement
    k_zero_int<<<(N + 255) / 256, 256, 0, stream>>>(cnt, N);
    k_count_loc<<<ge4, 256, 0, stream>>>(ei, cnt, lo, E);
    k_partial<<<nb, 256, 0, stream>>>(cnt, partials, N);
    k_scan_top<<<1, 256, 0, stream>>>(partials, blkoff, nb);
    k_apply<<<nb, 512, 0, stream>>>(cnt, blkoff, row_ptr, dinv, N, E);
    k_place<<<ge4, 256, 0, stream>>>(ei, row_ptr, lo, csr_src, E);

    // param prep
    k_bnfold<<<1, 256, 0, stream>>>(b1, g1, be1, m1, v1, s1, t1, 256);
    k_bnfold<<<1, 256, 0, stream>>>(b2, g2, be2, m2, v2, s2, t2, 256);
    k_w2bf<<<(128 * 256 + 255) / 256, 256, 0, stream>>>(W1, Wt1, 128, 256);
    k_w2bf<<<(256 * 256 + 255) / 256, 256, 0, stream>>>(W2, Wt2, 256, 256);
    k_w2bf<<<(256 * 32 + 255) / 256, 256, 0, stream>>>(W3, Wt3, 256, 32);
    k_x2bf<<<(N * 128 / 4 + 255) / 256, 256, 0, stream>>>(x, xbf, dinv, N * 128 / 4);

    // Layer 1: agg(xs,128) -> GEMM(128->256)+BN+ReLU+dinv -> bf16 (pre-scaled)
    agg_x<<<gagg, 256, 0, stream>>>(xbf, bufA, row_ptr, csr_src, dinv, N);
    g_mfma_lds<128, 64, 1, 2><<<dim3(128, 4), 256, 0, stream>>>(
        bufA, Wt1, bufB, N, 256, s1, t1, dinv, nT);

    // Layer 2: agg(h1s,256) -> GEMM(256->256)+BN+ReLU+dinv -> bf16 (pre-scaled)
    agg_h<<<gagg, 256, 0, stream>>>(bufB, bufA, row_ptr, csr_src, dinv, N);
    g_mfma_lds<256, 64, 1, 2><<<dim3(128, 4), 256, 0, stream>>>(
        bufA, Wt2, bufB, N, 256, s2, t2, dinv, nT);

    // Layer 3: GEMM(256->32) -> bf16, then agg + b3 + sigmoid
    g_mfma_lds<256, 32, 2, 2><<<dim3(512, 1), 256, 0, stream>>>(
        bufB, Wt3, z3, N, 32, (const float*)nullptr, (const float*)nullptr,
        (const float*)nullptr, nT);
    agg32_sig<<<gagg, 256, 0, stream>>>(z3, out, row_ptr, csr_src, dinv, b3, N);
}